// Round 1
// baseline (136.273 us; speedup 1.0000x reference)
//
#include <hip/hip_runtime.h>

#define D 256
#define NB 128
#define LX 64
#define LY 64
#define NV 53
#define VP 56          // padded V for float4 loads
#define WTS 129        // LDS stride (odd -> conflict-free staged writes & reads)
#define SLICE (LX*NB*VP)   // 458752 floats per array

// ws layout (floats): PS @0, PI @SLICE, MS @2*SLICE, MI @3*SLICE  (7.0 MB total)

__global__ __launch_bounds__(512) void p1_kernel(
    const float* __restrict__ prior, const float* __restrict__ modern,
    const float* __restrict__ Wsub, const float* __restrict__ bsub,
    const float* __restrict__ Wins, const float* __restrict__ bins,
    float* __restrict__ ws)
{
    __shared__ float WT[D * WTS];   // WT[d*129 + o]: o<53 -> Wsub[o][d], o in [53,106) -> Wins[o-53][d]
    const int tid = threadIdx.x;
    for (int i = tid; i < NV * D; i += 512) {
        const int v = i >> 8;
        const int d = i & (D - 1);
        WT[d * WTS + v]      = Wsub[i];
        WT[d * WTS + NV + v] = Wins[i];
    }
    __syncthreads();

    const int wave = __builtin_amdgcn_readfirstlane(tid >> 6);
    const int lane = tid & 63;
    const int o1 = lane;        // outputs 0..63
    const int o2 = lane + 64;   // outputs 64..105 (lanes 0..41)

    for (int r = 0; r < 8; ++r) {
        const int row    = blockIdx.x * 64 + wave * 8 + r;   // 0..16383
        const int side   = row >> 13;                        // 0: prior, 1: modern
        const int within = row & 8191;                       // x*128+b or y*128+b
        const float* __restrict__ src = (side ? modern : prior) + within * D;

        float acc1 = 0.f, acc2 = 0.f;
        #pragma unroll 4
        for (int d = 0; d < D; d += 4) {
            const float4 c = *reinterpret_cast<const float4*>(src + d);
            const float* wt = &WT[d * WTS];
            acc1 += c.x * wt[o1];
            acc1 += c.y * wt[WTS + o1];
            acc1 += c.z * wt[2*WTS + o1];
            acc1 += c.w * wt[3*WTS + o1];
            acc2 += c.x * wt[o2];
            acc2 += c.y * wt[WTS + o2];
            acc2 += c.z * wt[2*WTS + o2];
            acc2 += c.w * wt[3*WTS + o2];
        }

        float b1 = 0.f, b2 = 0.f;
        if (side) {   // fold biases into the modern side
            b1 = (o1 < NV) ? bsub[o1] : bins[o1 - NV];
            b2 = (o2 < 106) ? bins[o2 - NV] : 0.f;
        }
        const float v1 = acc1 + b1;
        const float v2 = acc2 + b2;

        float* __restrict__ base = ws + side * (2 * SLICE) + within * VP;
        if (o1 < NV) base[o1] = v1;                   // PS / MS
        else         base[SLICE + (o1 - NV)] = v1;    // PI / MI, v = 0..10
        if (o2 < 106) base[SLICE + (o2 - NV)] = v2;   // PI / MI, v = 11..52
    }
}

__global__ __launch_bounds__(256) void p2_kernel(
    const float* __restrict__ ws,
    const int* __restrict__ target, const int* __restrict__ srclen,
    const int* __restrict__ tgtlen, float* __restrict__ out)
{
    const int tid = threadIdx.x;
    const int b = tid & (NB - 1);
    const int x = blockIdx.x >> 5;
    const int y = ((blockIdx.x & 31) << 1) + (tid >> 7);

    const int sl = srclen[b], tl = tgtlen[b];
    const bool msk = (x < sl) && (y < tl);
    const int t = (y < LY - 1) ? target[y * NB + b] : -1;

    const float4* __restrict__ P = reinterpret_cast<const float4*>(ws + (x * NB + b) * VP);
    const float4* __restrict__ M = reinterpret_cast<const float4*>(ws + 2 * SLICE + (y * NB + b) * VP);
    const int S4 = SLICE / 4;

    float l[VP];

    // ---------- sub ----------
    #pragma unroll
    for (int i = 0; i < VP/4; ++i) {
        const float4 p = P[i];
        const float4 q = M[i];
        l[4*i+0] = p.x + q.x;
        l[4*i+1] = p.y + q.y;
        l[4*i+2] = p.z + q.z;
        l[4*i+3] = p.w + q.w;
    }
    float mx = l[0];
    #pragma unroll
    for (int v = 1; v < NV; ++v) mx = fmaxf(mx, l[v]);
    float s = 0.f, lt = 0.f;
    #pragma unroll
    for (int v = 0; v < NV; ++v) {
        s += __expf(l[v] - mx);
        if (v == t) lt = l[v];
    }
    const float lse = mx + __logf(s);
    out[(x * LY + y) * NB + b] = msk ? (l[NV-1] - lse) : 0.f;
    if (y < LY - 1)
        out[1048576 + (x * (LY-1) + y) * NB + b] = msk ? (lt - lse) : 0.f;

    // ---------- ins ----------
    #pragma unroll
    for (int i = 0; i < VP/4; ++i) {
        const float4 p = P[S4 + i];
        const float4 q = M[S4 + i];
        l[4*i+0] = p.x + q.x;
        l[4*i+1] = p.y + q.y;
        l[4*i+2] = p.z + q.z;
        l[4*i+3] = p.w + q.w;
    }
    float mx2 = l[0];
    #pragma unroll
    for (int v = 1; v < NV; ++v) mx2 = fmaxf(mx2, l[v]);
    float s2 = 0.f, lt2 = 0.f;
    #pragma unroll
    for (int v = 0; v < NV; ++v) {
        s2 += __expf(l[v] - mx2);
        if (v == t) lt2 = l[v];
    }
    const float lse2 = mx2 + __logf(s2);
    out[524288 + (x * LY + y) * NB + b] = msk ? (l[NV-1] - lse2) : 0.f;
    if (y < LY - 1)
        out[1564672 + (x * (LY-1) + y) * NB + b] = msk ? (lt2 - lse2) : 0.f;
}

extern "C" void kernel_launch(void* const* d_in, const int* in_sizes, int n_in,
                              void* d_out, int out_size, void* d_ws, size_t ws_size,
                              hipStream_t stream) {
    const float* prior  = (const float*)d_in[0];
    const float* modern = (const float*)d_in[1];
    const float* Wsub   = (const float*)d_in[2];
    const float* bsub   = (const float*)d_in[3];
    const float* Wins   = (const float*)d_in[4];
    const float* bins   = (const float*)d_in[5];
    const int*   target = (const int*)d_in[6];
    const int*   srclen = (const int*)d_in[7];
    const int*   tgtlen = (const int*)d_in[8];
    float* ws  = (float*)d_ws;
    float* out = (float*)d_out;

    // Pass 1: 16384 rows (2 sides x 8192), 64 rows/block, 8 waves x 8 rows
    p1_kernel<<<256, 512, 0, stream>>>(prior, modern, Wsub, bsub, Wins, bins, ws);
    // Pass 2: one thread per (x,y,b); block = (2 y) x 128 b
    p2_kernel<<<2048, 256, 0, stream>>>(ws, target, srclen, tgtlen, out);
}

// Round 2
// 61.815 us; speedup vs baseline: 2.2045x; 2.2045x over previous
//
#include <hip/hip_runtime.h>

#define D   256
#define NB  128
#define NV  53
#define WTS 108          // LDS row stride in floats (>=106, conflict-free: lanes read consecutive o)
#define NR  8192         // rows per side (64*128)
#define V4  14           // padded v-groups (56 v slots)
#define SL  (V4*NR*4)    // floats per array slice = 458752

// ws layout (floats): PS4 @0, PI4 @SL, MS4 @2*SL, MI4 @3*SL  (7.34 MB)
// element (v, row) lives at  slice + ((v>>2)*NR + row)*4 + (v&3)

__global__ __launch_bounds__(512) void p1_kernel(
    const float* __restrict__ prior, const float* __restrict__ modern,
    const float* __restrict__ Wsub, const float* __restrict__ bsub,
    const float* __restrict__ Wins, const float* __restrict__ bins,
    float* __restrict__ ws)
{
    __shared__ float WT[D * WTS + 32];   // WT[d*WTS + o]: o<53 -> Wsub[o][d], o in [53,106) -> Wins[o-53][d]
    const int tid = threadIdx.x;
    for (int i = tid; i < NV * D; i += 512) {
        const int v = i >> 8;
        const int d = i & (D - 1);
        WT[d * WTS + v]      = Wsub[i];
        WT[d * WTS + NV + v] = Wins[i];
    }
    __syncthreads();

    const int wave = __builtin_amdgcn_readfirstlane(tid >> 6);
    const int lane = tid & 63;
    const int o1   = lane;                    // outputs 0..63
    const int o2c  = (lane + 64 > 105) ? 105 : lane + 64;   // outputs 64..105 (lanes 0..41 active)
    const bool act2 = lane < 42;

    const int rowbase = blockIdx.x * 64 + wave * 8;   // uniform per wave
    const int side    = rowbase >> 13;                // 0: prior, 1: modern
    const int within0 = rowbase & (NR - 1);
    const float* __restrict__ src = (side ? modern : prior) + (size_t)within0 * D;

    // fold biases into the modern side
    float b1 = 0.f, b2 = 0.f;
    if (side) {
        b1 = (o1 < NV) ? bsub[o1] : bins[o1 - NV];
        b2 = bins[o2c - NV];                          // o2c-53 in 11..52
    }

    float acc1[8], acc2[8];
    #pragma unroll
    for (int r = 0; r < 8; ++r) { acc1[r] = 0.f; acc2[r] = 0.f; }

    #pragma unroll 2
    for (int d = 0; d < D; d += 4) {
        float4 c[8];
        #pragma unroll
        for (int r = 0; r < 8; ++r)
            c[r] = *reinterpret_cast<const float4*>(src + r * D + d);
        float w1[4], w2[4];
        #pragma unroll
        for (int k = 0; k < 4; ++k) {
            w1[k] = WT[(d + k) * WTS + o1];
            w2[k] = WT[(d + k) * WTS + o2c];
        }
        #pragma unroll
        for (int r = 0; r < 8; ++r) {
            acc1[r] += c[r].x * w1[0] + c[r].y * w1[1] + c[r].z * w1[2] + c[r].w * w1[3];
            acc2[r] += c[r].x * w2[0] + c[r].y * w2[1] + c[r].z * w2[2] + c[r].w * w2[3];
        }
    }

    float* __restrict__ base = ws + side * (2 * SL);
    #pragma unroll
    for (int r = 0; r < 8; ++r) {
        const int xb = within0 + r;
        const float v1 = acc1[r] + b1;
        const float v2 = acc2[r] + b2;
        if (o1 < NV) base[((o1 >> 2) * NR + xb) * 4 + (o1 & 3)] = v1;          // sub, v=o1
        else {
            const int vi = o1 - NV;                                             // ins, v=0..10
            base[SL + ((vi >> 2) * NR + xb) * 4 + (vi & 3)] = v1;
        }
        if (act2) {
            const int vi = o2c - NV;                                            // ins, v=11..52
            base[SL + ((vi >> 2) * NR + xb) * 4 + (vi & 3)] = v2;
        }
    }
}

__global__ __launch_bounds__(256) void p2_kernel(
    const float* __restrict__ ws,
    const int* __restrict__ target, const int* __restrict__ srclen,
    const int* __restrict__ tgtlen, float* __restrict__ out)
{
    const int tid = threadIdx.x;
    const int b = tid & (NB - 1);
    const int x = blockIdx.x >> 5;
    const int y = ((blockIdx.x & 31) << 1) | (tid >> 7);
    const int xb = x * NB + b;
    const int yb = y * NB + b;

    const int sl = srclen[b], tl = tgtlen[b];
    const bool msk  = (x < sl) && (y < tl);
    const bool hasT = (y < 63);
    const int  t    = hasT ? target[y * NB + b] : 0;

    const float4* __restrict__ PS = reinterpret_cast<const float4*>(ws);
    const float4* __restrict__ PI = reinterpret_cast<const float4*>(ws + SL);
    const float4* __restrict__ MS = reinterpret_cast<const float4*>(ws + 2 * SL);
    const float4* __restrict__ MI = reinterpret_cast<const float4*>(ws + 3 * SL);

    float l[56];

    // ---------- sub ----------
    #pragma unroll
    for (int v4 = 0; v4 < V4; ++v4) {
        const float4 p = PS[v4 * NR + xb];
        const float4 m = MS[v4 * NR + yb];
        l[4*v4+0] = p.x + m.x;
        l[4*v4+1] = p.y + m.y;
        l[4*v4+2] = p.z + m.z;
        l[4*v4+3] = p.w + m.w;
    }
    float mx = l[0];
    #pragma unroll
    for (int v = 1; v < NV; ++v) mx = fmaxf(mx, l[v]);
    float s = 0.f;
    #pragma unroll
    for (int v = 0; v < NV; ++v) s += __expf(l[v] - mx);
    const float lse = mx + __logf(s);
    const float lt  = ws[((t >> 2) * NR + xb) * 4 + (t & 3)]
                    + ws[2 * SL + ((t >> 2) * NR + yb) * 4 + (t & 3)];
    out[(x * 64 + y) * NB + b] = msk ? (l[NV-1] - lse) : 0.f;
    if (hasT)
        out[1048576 + (x * 63 + y) * NB + b] = msk ? (lt - lse) : 0.f;

    // ---------- ins ----------
    #pragma unroll
    for (int v4 = 0; v4 < V4; ++v4) {
        const float4 p = PI[v4 * NR + xb];
        const float4 m = MI[v4 * NR + yb];
        l[4*v4+0] = p.x + m.x;
        l[4*v4+1] = p.y + m.y;
        l[4*v4+2] = p.z + m.z;
        l[4*v4+3] = p.w + m.w;
    }
    float mx2 = l[0];
    #pragma unroll
    for (int v = 1; v < NV; ++v) mx2 = fmaxf(mx2, l[v]);
    float s2 = 0.f;
    #pragma unroll
    for (int v = 0; v < NV; ++v) s2 += __expf(l[v] - mx2);
    const float lse2 = mx2 + __logf(s2);
    const float lt2  = ws[SL + ((t >> 2) * NR + xb) * 4 + (t & 3)]
                     + ws[3 * SL + ((t >> 2) * NR + yb) * 4 + (t & 3)];
    out[524288 + (x * 64 + y) * NB + b] = msk ? (l[NV-1] - lse2) : 0.f;
    if (hasT)
        out[1564672 + (x * 63 + y) * NB + b] = msk ? (lt2 - lse2) : 0.f;
}

extern "C" void kernel_launch(void* const* d_in, const int* in_sizes, int n_in,
                              void* d_out, int out_size, void* d_ws, size_t ws_size,
                              hipStream_t stream) {
    const float* prior  = (const float*)d_in[0];
    const float* modern = (const float*)d_in[1];
    const float* Wsub   = (const float*)d_in[2];
    const float* bsub   = (const float*)d_in[3];
    const float* Wins   = (const float*)d_in[4];
    const float* bins   = (const float*)d_in[5];
    const int*   target = (const int*)d_in[6];
    const int*   srclen = (const int*)d_in[7];
    const int*   tgtlen = (const int*)d_in[8];
    float* ws  = (float*)d_ws;
    float* out = (float*)d_out;

    // Pass 1: 16384 rows (2 sides x 8192), 64 rows/block, 8 waves x 8 rows each
    p1_kernel<<<256, 512, 0, stream>>>(prior, modern, Wsub, bsub, Wins, bins, ws);
    // Pass 2: one thread per (x,y,b); block = (2 y) x 128 b
    p2_kernel<<<2048, 256, 0, stream>>>(ws, target, srclen, tgtlen, out);
}

// Round 3
// 59.264 us; speedup vs baseline: 2.2994x; 1.0430x over previous
//
#include <hip/hip_runtime.h>

#define D   256
#define NB  128
#define NV  53
#define NR  8192         // rows per side (64*128)
#define V4  14           // padded v-groups (56 v slots)
#define SL  (V4*NR*4)    // floats per array slice = 458752
#define WTP 112          // padded output count for WT rows
#define WSOFF (4*SL)     // float offset of WT inside ws

// ws layout (floats): PS4 @0, PI4 @SL, MS4 @2*SL, MI4 @3*SL, WT @WSOFF (256x112)
// element (v, row) of a slice lives at  slice + ((v>>2)*NR + row)*4 + (v&3)

// ---- p0: transpose W into WT[d][o] (o<53: Wsub, 53..105: Wins, rest 0) ----
__global__ void p0_kernel(const float* __restrict__ Wsub,
                          const float* __restrict__ Wins,
                          float* __restrict__ WT)
{
    const int d = blockIdx.x;      // 0..255
    const int o = threadIdx.x;     // 0..111
    float v = 0.f;
    if (o < NV)       v = Wsub[o * D + d];
    else if (o < 106) v = Wins[(o - NV) * D + d];
    WT[d * WTP + o] = v;
}

// ---- p1: [16384 x 256] x [256 x 106] GEMM, WT streamed from L1/L2 ----
__global__ __launch_bounds__(256) void p1_kernel(
    const float* __restrict__ prior, const float* __restrict__ modern,
    const float* __restrict__ bsub, const float* __restrict__ bins,
    const float* __restrict__ WT, float* __restrict__ ws)
{
    const int tid  = threadIdx.x;
    const int wave = __builtin_amdgcn_readfirstlane(tid >> 6);
    const int lane = tid & 63;
    const int o1   = lane;                                   // outputs 0..63
    const int o2c  = (lane + 64 > 105) ? 105 : lane + 64;    // outputs 64..105
    const bool act2 = lane < 42;

    const int row0    = blockIdx.x * 16 + wave * 4;   // 4 rows per wave
    const int side    = row0 >> 13;                   // 0: prior, 1: modern
    const int within0 = row0 & (NR - 1);
    const float* __restrict__ src = (side ? modern : prior) + (size_t)within0 * D;

    // fold biases into the modern side
    float b1 = 0.f, b2 = 0.f;
    if (side) {
        b1 = (o1 < NV) ? bsub[o1] : bins[o1 - NV];
        b2 = bins[o2c - NV];
    }

    const float* __restrict__ wp1 = WT + o1;
    const float* __restrict__ wp2 = WT + o2c;

    float acc1[4], acc2[4];
    #pragma unroll
    for (int r = 0; r < 4; ++r) { acc1[r] = 0.f; acc2[r] = 0.f; }

    #pragma unroll 2
    for (int d = 0; d < D; d += 4) {
        float4 c[4];
        #pragma unroll
        for (int r = 0; r < 4; ++r)
            c[r] = *reinterpret_cast<const float4*>(src + r * D + d);
        float w1[4], w2[4];
        #pragma unroll
        for (int k = 0; k < 4; ++k) {
            w1[k] = wp1[(d + k) * WTP];
            w2[k] = wp2[(d + k) * WTP];
        }
        #pragma unroll
        for (int r = 0; r < 4; ++r) {
            acc1[r] += c[r].x * w1[0] + c[r].y * w1[1] + c[r].z * w1[2] + c[r].w * w1[3];
            acc2[r] += c[r].x * w2[0] + c[r].y * w2[1] + c[r].z * w2[2] + c[r].w * w2[3];
        }
    }

    float* __restrict__ base = ws + side * (2 * SL);
    #pragma unroll
    for (int r = 0; r < 4; ++r) {
        const int xb = within0 + r;
        const float v1 = acc1[r] + b1;
        const float v2 = acc2[r] + b2;
        if (o1 < NV) base[((o1 >> 2) * NR + xb) * 4 + (o1 & 3)] = v1;   // sub, v=o1
        else {
            const int vi = o1 - NV;                                      // ins, v=0..10
            base[SL + ((vi >> 2) * NR + xb) * 4 + (vi & 3)] = v1;
        }
        if (act2) {
            const int vi = o2c - NV;                                     // ins, v=11..52
            base[SL + ((vi >> 2) * NR + xb) * 4 + (vi & 3)] = v2;
        }
    }
}

// ---- p2: l = P[x]+M[y], logsumexp over 53, 4 x's per thread (M cached in regs) ----
__global__ __launch_bounds__(256) void p2_kernel(
    const float* __restrict__ ws,
    const int* __restrict__ target, const int* __restrict__ srclen,
    const int* __restrict__ tgtlen, float* __restrict__ out)
{
    const int tid = threadIdx.x;
    const int b   = tid & (NB - 1);
    const int x0  = blockIdx.x >> 5;                         // 0..15
    const int y   = ((blockIdx.x & 31) << 1) | (tid >> 7);   // 0..63
    const int yb  = y * NB + b;

    const int sl = srclen[b], tl = tgtlen[b];
    const bool ymask = (y < tl);
    const bool hasT  = (y < 63);
    const int  t     = hasT ? target[y * NB + b] : 0;
    const int  tgrp  = (t >> 2) * NR;
    const int  tsub  = t & 3;

    const float4* __restrict__ PS = reinterpret_cast<const float4*>(ws);
    const float4* __restrict__ PI = reinterpret_cast<const float4*>(ws + SL);
    const float4* __restrict__ MS = reinterpret_cast<const float4*>(ws + 2 * SL);
    const float4* __restrict__ MI = reinterpret_cast<const float4*>(ws + 3 * SL);

    float m[56], l[56];

    // ================= sub =================
    #pragma unroll
    for (int v4 = 0; v4 < V4; ++v4) {
        const float4 q = MS[v4 * NR + yb];
        m[4*v4+0] = q.x; m[4*v4+1] = q.y; m[4*v4+2] = q.z; m[4*v4+3] = q.w;
    }
    const float mlt = ws[2 * SL + (tgrp + yb) * 4 + tsub];

    #pragma unroll
    for (int xi = 0; xi < 4; ++xi) {
        const int x  = x0 + (xi << 4);
        const int xb = x * NB + b;
        const bool msk = (x < sl) && ymask;
        #pragma unroll
        for (int v4 = 0; v4 < V4; ++v4) {
            const float4 p = PS[v4 * NR + xb];
            l[4*v4+0] = p.x + m[4*v4+0];
            l[4*v4+1] = p.y + m[4*v4+1];
            l[4*v4+2] = p.z + m[4*v4+2];
            l[4*v4+3] = p.w + m[4*v4+3];
        }
        float mx = l[0];
        #pragma unroll
        for (int v = 1; v < NV; ++v) mx = fmaxf(mx, l[v]);
        float s = 0.f;
        #pragma unroll
        for (int v = 0; v < NV; ++v) s += __expf(l[v] - mx);
        const float lse = mx + __logf(s);
        const float lt  = ws[(tgrp + xb) * 4 + tsub] + mlt;
        out[(x * 64 + y) * NB + b] = msk ? (l[NV-1] - lse) : 0.f;
        if (hasT)
            out[1048576 + (x * 63 + y) * NB + b] = msk ? (lt - lse) : 0.f;
    }

    // ================= ins =================
    #pragma unroll
    for (int v4 = 0; v4 < V4; ++v4) {
        const float4 q = MI[v4 * NR + yb];
        m[4*v4+0] = q.x; m[4*v4+1] = q.y; m[4*v4+2] = q.z; m[4*v4+3] = q.w;
    }
    const float mlt2 = ws[3 * SL + (tgrp + yb) * 4 + tsub];

    #pragma unroll
    for (int xi = 0; xi < 4; ++xi) {
        const int x  = x0 + (xi << 4);
        const int xb = x * NB + b;
        const bool msk = (x < sl) && ymask;
        #pragma unroll
        for (int v4 = 0; v4 < V4; ++v4) {
            const float4 p = PI[v4 * NR + xb];
            l[4*v4+0] = p.x + m[4*v4+0];
            l[4*v4+1] = p.y + m[4*v4+1];
            l[4*v4+2] = p.z + m[4*v4+2];
            l[4*v4+3] = p.w + m[4*v4+3];
        }
        float mx = l[0];
        #pragma unroll
        for (int v = 1; v < NV; ++v) mx = fmaxf(mx, l[v]);
        float s = 0.f;
        #pragma unroll
        for (int v = 0; v < NV; ++v) s += __expf(l[v] - mx);
        const float lse = mx + __logf(s);
        const float lt  = ws[SL + (tgrp + xb) * 4 + tsub] + mlt2;
        out[524288 + (x * 64 + y) * NB + b] = msk ? (l[NV-1] - lse) : 0.f;
        if (hasT)
            out[1564672 + (x * 63 + y) * NB + b] = msk ? (lt - lse) : 0.f;
    }
}

extern "C" void kernel_launch(void* const* d_in, const int* in_sizes, int n_in,
                              void* d_out, int out_size, void* d_ws, size_t ws_size,
                              hipStream_t stream) {
    const float* prior  = (const float*)d_in[0];
    const float* modern = (const float*)d_in[1];
    const float* Wsub   = (const float*)d_in[2];
    const float* bsub   = (const float*)d_in[3];
    const float* Wins   = (const float*)d_in[4];
    const float* bins   = (const float*)d_in[5];
    const int*   target = (const int*)d_in[6];
    const int*   srclen = (const int*)d_in[7];
    const int*   tgtlen = (const int*)d_in[8];
    float* ws  = (float*)d_ws;
    float* out = (float*)d_out;
    float* WT  = ws + WSOFF;

    // p0: transpose W into WT[d][112]
    p0_kernel<<<256, 112, 0, stream>>>(Wsub, Wins, WT);
    // p1: 16384 rows, 4 rows/wave, 4 waves/block -> 1024 blocks
    p1_kernel<<<1024, 256, 0, stream>>>(prior, modern, bsub, bins, WT, ws);
    // p2: 4 x's per thread; block = (2 y) x 128 b -> 512 blocks
    p2_kernel<<<512, 256, 0, stream>>>(ws, target, srclen, tgtlen, out);
}

// Round 4
// 36.012 us; speedup vs baseline: 3.7841x; 1.6457x over previous
//
#include <hip/hip_runtime.h>

#define D   256
#define NB  128
#define NV  53
#define NR  8192            // rows per side (64*128)
#define V4  14              // v-groups of 4 (56 slots)
#define SLB (V4*NR*4)       // 458752 bf16 elements per slice

// ws (bf16/ushort units): PS @0, PI @SLB, MS @2*SLB, MI @3*SLB  (3.67 MB)
// element (v, row) of a slice:  ((v>>2)*NR + row)*4 + (v&3)

typedef float  f4 __attribute__((ext_vector_type(4)));
typedef short  s8 __attribute__((ext_vector_type(8)));

__device__ __forceinline__ ushort f2bf(float f) {            // RNE f32 -> bf16
    uint u = __float_as_uint(f);
    u += 0x7fff + ((u >> 16) & 1);
    return (ushort)(u >> 16);
}
__device__ __forceinline__ float bflo(uint w) { return __uint_as_float(w << 16); }
__device__ __forceinline__ float bfhi(uint w) { return __uint_as_float(w & 0xffff0000u); }

// ---- p1: [16384 x 256] x [256 x 106] GEMM via bf16 MFMA, LDS-resident W ----
// grid 256 x 256thr: 4 waves/block, 1 tile(16 rows)/wave, 1024 tiles total.
__global__ __launch_bounds__(256) void p1_kernel(
    const float* __restrict__ prior, const float* __restrict__ modern,
    const float* __restrict__ Wsub, const float* __restrict__ bsub,
    const float* __restrict__ Wins, const float* __restrict__ bins,
    ushort* __restrict__ wsb)
{
    // B fragments: WB[((nt*8+s)*64 + lane)*8 + j] = W^T[32s+8*(lane>>4)+j][nt*16+(lane&15)]
    __shared__ ushort WB[3584 * 8];        // 57344 B
    const int tid = threadIdx.x;

    #pragma unroll
    for (int i = 0; i < 14; ++i) {
        const int F  = tid + 256 * i;      // fragment-slot 0..3583
        const int l  = F & 63, s = (F >> 6) & 7, nt = F >> 9;
        const int o  = nt * 16 + (l & 15);
        const int d0 = 32 * s + 8 * (l >> 4);
        s8 bfr;
        if (o < NV) {
            const float* w = Wsub + o * D + d0;
            #pragma unroll
            for (int j = 0; j < 8; ++j) bfr[j] = (short)f2bf(w[j]);
        } else if (o < 106) {
            const float* w = Wins + (o - NV) * D + d0;
            #pragma unroll
            for (int j = 0; j < 8; ++j) bfr[j] = (short)f2bf(w[j]);
        } else {
            #pragma unroll
            for (int j = 0; j < 8; ++j) bfr[j] = 0;
        }
        *(s8*)&WB[F * 8] = bfr;
    }
    __syncthreads();

    const int wave = tid >> 6, lane = tid & 63;
    const int tile = blockIdx.x * 4 + wave;           // 0..1023
    const int side = tile >> 9;                       // 0: prior, 1: modern
    const int row0 = (tile & 511) << 4;
    const int lrow = lane & 15, lk = lane >> 4;
    const float* __restrict__ src =
        (side ? modern : prior) + (size_t)(row0 + lrow) * D + lk * 8;

    f4 acc[7];
    #pragma unroll
    for (int nt = 0; nt < 7; ++nt) { acc[nt][0]=0.f; acc[nt][1]=0.f; acc[nt][2]=0.f; acc[nt][3]=0.f; }

    #pragma unroll
    for (int s = 0; s < 8; ++s) {
        const f4 c0 = *(const f4*)(src + 32 * s);
        const f4 c1 = *(const f4*)(src + 32 * s + 4);
        s8 a;
        a[0]=(short)f2bf(c0[0]); a[1]=(short)f2bf(c0[1]);
        a[2]=(short)f2bf(c0[2]); a[3]=(short)f2bf(c0[3]);
        a[4]=(short)f2bf(c1[0]); a[5]=(short)f2bf(c1[1]);
        a[6]=(short)f2bf(c1[2]); a[7]=(short)f2bf(c1[3]);
        #pragma unroll
        for (int nt = 0; nt < 7; ++nt) {
            const s8 bfr = *(const s8*)&WB[(((nt << 3) + s) * 64 + lane) * 8];
            acc[nt] = __builtin_amdgcn_mfma_f32_16x16x32_bf16(a, bfr, acc[nt], 0, 0, 0);
        }
    }

    // C/D: col(v) = nt*16 + (lane&15), row = row0 + 4*(lane>>4) + reg   [m89]
    ushort* __restrict__ base = wsb + side * (2 * SLB);
    #pragma unroll
    for (int nt = 0; nt < 7; ++nt) {
        const int v = nt * 16 + lrow;
        if (v < 106) {
            float bias = 0.f;
            if (side) bias = (v < NV) ? bsub[v] : bins[v - NV];
            const int   vi = (v < NV) ? v : v - NV;
            ushort* sl     = base + ((v < NV) ? 0 : SLB);
            const int a0   = (vi >> 2) * (NR * 4) + (vi & 3);
            #pragma unroll
            for (int r = 0; r < 4; ++r) {
                const int row = row0 + 4 * lk + r;
                sl[a0 + row * 4] = f2bf(acc[nt][r] + bias);
            }
        }
    }
}

// ---- p2: l = P[x]+M[y], logsumexp over 53, 4 x's/thread, M reg-cached ----
__global__ __launch_bounds__(256) void p2_kernel(
    const ushort* __restrict__ wsb,
    const int* __restrict__ target, const int* __restrict__ srclen,
    const int* __restrict__ tgtlen, float* __restrict__ out)
{
    const int tid = threadIdx.x;
    const int b   = tid & 127;
    const int bid = blockIdx.x;
    const int xt  = ((bid & 7) << 1) | ((bid >> 3) & 1);   // 0..15; bid%8 pins x-band per XCD
    const int y   = ((bid >> 4) << 1) | (tid >> 7);        // 0..63
    const int yb  = y * NB + b;

    const int sl = srclen[b], tl = tgtlen[b];
    const bool ymask = y < tl;
    const bool hasT  = y < 63;
    const int  t     = hasT ? target[y * NB + b] : 0;
    const int  toff  = (t >> 2) * (NR * 4) + (t & 3);

    float m[56], l[56];

    #pragma unroll
    for (int dist = 0; dist < 2; ++dist) {                 // 0: sub, 1: ins
        const ushort* __restrict__ P = wsb + dist * SLB;
        const ushort* __restrict__ M = wsb + (2 + dist) * SLB;

        #pragma unroll
        for (int g = 0; g < V4; ++g) {
            const uint2 q = *(const uint2*)(M + (g * NR + yb) * 4);
            m[4*g+0] = bflo(q.x); m[4*g+1] = bfhi(q.x);
            m[4*g+2] = bflo(q.y); m[4*g+3] = bfhi(q.y);
        }
        const float mlt = bflo((uint)M[toff + yb * 4]);

        float* __restrict__ o0 = out + dist * 524288;              // del / end
        float* __restrict__ o1 = out + 1048576 + dist * 516096;    // sub_probs / ins_probs

        #pragma unroll
        for (int xi = 0; xi < 4; ++xi) {
            const int x  = (xt << 2) + xi;
            const int xb = x * NB + b;
            const bool msk = (x < sl) & ymask;
            #pragma unroll
            for (int g = 0; g < V4; ++g) {
                const uint2 q = *(const uint2*)(P + (g * NR + xb) * 4);
                l[4*g+0] = bflo(q.x) + m[4*g+0];
                l[4*g+1] = bfhi(q.x) + m[4*g+1];
                l[4*g+2] = bflo(q.y) + m[4*g+2];
                l[4*g+3] = bfhi(q.y) + m[4*g+3];
            }
            float mx = l[0];
            #pragma unroll
            for (int v = 1; v < NV; ++v) mx = fmaxf(mx, l[v]);
            float ssum = 0.f;
            #pragma unroll
            for (int v = 0; v < NV; ++v) ssum += __expf(l[v] - mx);
            const float lse = mx + __logf(ssum);
            o0[((x << 6) | y) * NB + b] = msk ? (l[NV - 1] - lse) : 0.f;
            if (hasT) {
                const float lt = bflo((uint)P[toff + xb * 4]) + mlt;
                o1[(x * 63 + y) * NB + b] = msk ? (lt - lse) : 0.f;
            }
        }
    }
}

extern "C" void kernel_launch(void* const* d_in, const int* in_sizes, int n_in,
                              void* d_out, int out_size, void* d_ws, size_t ws_size,
                              hipStream_t stream) {
    const float* prior  = (const float*)d_in[0];
    const float* modern = (const float*)d_in[1];
    const float* Wsub   = (const float*)d_in[2];
    const float* bsub   = (const float*)d_in[3];
    const float* Wins   = (const float*)d_in[4];
    const float* bins   = (const float*)d_in[5];
    const int*   target = (const int*)d_in[6];
    const int*   srclen = (const int*)d_in[7];
    const int*   tgtlen = (const int*)d_in[8];
    ushort* wsb = (ushort*)d_ws;
    float*  out = (float*)d_out;

    p1_kernel<<<256, 256, 0, stream>>>(prior, modern, Wsub, bsub, Wins, bins, wsb);
    p2_kernel<<<512, 256, 0, stream>>>(wsb, target, srclen, tgtlen, out);
}